// Round 4
// baseline (373.945 us; speedup 1.0000x reference)
//
#include <hip/hip_runtime.h>

typedef unsigned int u32;
typedef unsigned long long u64;

// ---------------------------------------------------------------------------
// Exact reproduction of (VERIFIED bit-exact in round 3):
//   u    = jax.random.uniform(jax.random.key(42), (256,1024,256))
//          [threefry2x32, jax_threefry_partitionable=True 32-bit path:
//           elem i = (w0 ^ w1) of threefry2x32_20(key=(0,42), block=(0,i))]
//   rank = argsort(argsort(u, -1), -1)      (stable -> lex order on (value,idx))
//   n1   = round_half_even(x * 256)
//   out  = (rank < n1) ? 1.0f : 0.0f
//
// R4 restructure: the R3 kernel (1 row/wave, tie-epilogue) measured 350us vs
// ~90us issue-bound model -> serial VALU->SALU->branch chain in the radix-
// select loop left the SIMD starved. This version:
//   * 4 rows per wave (16 elems/lane): 4 independent select chains interleave
//   * distinct 31-bit keys K = (m<<8)|idx  -> stable-tie logic vanishes
//     (rank(b) < n1  <=>  K_b among n1 smallest under total order)
//   * branchless per-row step, freeze on clean cut, single all-done exit
// ---------------------------------------------------------------------------

__device__ __forceinline__ u32 rotl32(u32 x, int r) {
  return (x << r) | (x >> (32 - r));   // -> v_alignbit_b32
}

// Threefry-2x32, 20 rounds, key (0, 42), block (0, i). Returns w0 ^ w1.
__device__ __forceinline__ u32 threefry_xor(u32 i) {
  const u32 ks0 = 0u;
  const u32 ks1 = 42u;
  const u32 ks2 = 0x1BD11BF0u;   // 0x1BD11BDA ^ 0 ^ 42
  u32 x0 = 0u + ks0;
  u32 x1 = i + ks1;
#define TFR(r) { x0 += x1; x1 = rotl32(x1, (r)); x1 ^= x0; }
  TFR(13) TFR(15) TFR(26) TFR(6)
  x0 += ks1; x1 += ks2 + 1u;
  TFR(17) TFR(29) TFR(16) TFR(24)
  x0 += ks2; x1 += ks0 + 2u;
  TFR(13) TFR(15) TFR(26) TFR(6)
  x0 += ks0; x1 += ks1 + 3u;
  TFR(17) TFR(29) TFR(16) TFR(24)
  x0 += ks1; x1 += ks2 + 4u;
  TFR(13) TFR(15) TFR(26) TFR(6)
  x0 += ks2; x1 += ks0 + 5u;
#undef TFR
  return x0 ^ x1;
}

// One wave64 owns FOUR rows of 256 bits; lane owns bits b = 4*lane + {0..3}
// of each row. Key K = (rand23 << 8) | b  -- all distinct within a row.
__global__ __launch_bounds__(256) void bitinput_kernel(
    const float* __restrict__ x, float* __restrict__ out, int nrows) {
  const int lane  = threadIdx.x & 63;
  const int wid   = threadIdx.x >> 6;
  const int row0  = ((blockIdx.x << 2) + wid) << 2;   // 4 rows per wave
  if (row0 >= nrows) return;

  const u32 idx0 = (u32)lane << 2;                    // elem index within row

  // ---- PRNG: 16 independent chains, pack distinct keys ----
  u32 K[4][4];
#pragma unroll
  for (int r = 0; r < 4; ++r) {
    const u32 gbase = ((u32)(row0 + r)) << 8;         // flat element index base
#pragma unroll
    for (int k = 0; k < 4; ++k) {
      const u32 b = idx0 + (u32)k;
      K[r][k] = ((threefry_xor(gbase + b) >> 9) << 8) | b;  // (m<<8)|idx, 31 bits
    }
  }

  // n1_r = round-half-even(x*256); exact in f32. Wave-uniform scalars.
  int n1[4];
#pragma unroll
  for (int r = 0; r < 4; ++r)
    n1[r] = __builtin_amdgcn_readfirstlane((int)rintf(x[row0 + r] * 256.0f));

  // ---- 4 interleaved radix binary searches over 31-bit distinct keys ----
  // T accumulates the greatest value with count_less(T) <= n1-1 (i.e. T ends
  // at the (n1-1)-th order statistic), unless a clean cut count_less(mid)==n1
  // freezes T=mid early (then selection is K < T with no boundary element).
  u32 T[4]    = {0u, 0u, 0u, 0u};
  u32 done[4] = {0u, 0u, 0u, 0u};
#pragma unroll 1
  for (int bit = 30; bit >= 0; --bit) {
    const u32 b = 1u << bit;
#pragma unroll
    for (int r = 0; r < 4; ++r) {
      const u32 mid = T[r] | b;
      const int cnt = __popcll(__ballot(K[r][0] < mid))
                    + __popcll(__ballot(K[r][1] < mid))
                    + __popcll(__ballot(K[r][2] < mid))
                    + __popcll(__ballot(K[r][3] < mid));
      const u32 take = (done[r] == 0u) & (u32)(cnt <= n1[r]);
      T[r] = take ? mid : T[r];
      done[r] |= (u32)(cnt == n1[r]);
    }
    if (done[0] & done[1] & done[2] & done[3]) break;
  }

  // ---- emit: done -> K < T (clean cut); else K <= T (T = boundary key) ----
#pragma unroll
  for (int r = 0; r < 4; ++r) {
    u32 Tsel = done[r] ? T[r] : (T[r] + 1u);
    if (n1[r] == 0) Tsel = 0u;    // guard: not-done fallthrough would pick K==0
    float4 o;
    o.x = (K[r][0] < Tsel) ? 1.0f : 0.0f;
    o.y = (K[r][1] < Tsel) ? 1.0f : 0.0f;
    o.z = (K[r][2] < Tsel) ? 1.0f : 0.0f;
    o.w = (K[r][3] < Tsel) ? 1.0f : 0.0f;
    reinterpret_cast<float4*>(out)[((row0 + r) << 6) + lane] = o;
  }
}

extern "C" void kernel_launch(void* const* d_in, const int* in_sizes, int n_in,
                              void* d_out, int out_size, void* d_ws, size_t ws_size,
                              hipStream_t stream) {
  const float* x = (const float*)d_in[0];
  float* out = (float*)d_out;
  const int nrows = in_sizes[0];                 // 256*1024 = 262144 bitstreams
  // 4 waves/block, 4 rows/wave -> 16 rows/block
  const int blocks = (nrows + 15) >> 4;
  hipLaunchKernelGGL(bitinput_kernel, dim3(blocks), dim3(256), 0, stream,
                     x, out, nrows);
}

// Round 5
// 350.812 us; speedup vs baseline: 1.0659x; 1.0659x over previous
//
#include <hip/hip_runtime.h>

typedef unsigned int u32;
typedef unsigned long long u64;

// ---------------------------------------------------------------------------
// Exact reproduction of (VERIFIED bit-exact in rounds 3/4):
//   u    = jax.random.uniform(jax.random.key(42), (256,1024,256))
//          [threefry2x32, jax_threefry_partitionable=True 32-bit path:
//           elem i = (w0 ^ w1) of threefry2x32_20(key=(0,42), block=(0,i))]
//   rank = argsort(argsort(u, -1), -1)      (stable -> lex order on (value,idx))
//   n1   = round_half_even(x * 256)
//   out  = (rank < n1) ? 1.0f : 0.0f
//
// R5: instruction diet. R4 measured 184us @ VALUBusy 98% (= issue-bound,
// ~211 lane-ops/elem vs ~91 modeled). Fixes:
//   * rotl via v_alignbit_b32 builtin (1 instr guaranteed, not 3)
//   * radix-select loop: only the 16 v_cmp are vector; T/done/cnt/n1 are
//     wave-uniform -> SALU (co-issues under VALU), early exit preserved
// Selection math (verified on HW in R4): distinct keys K=(m23<<8)|idx make
// argsort's stable tie-break a total lex order; descend 31 bits maintaining
// count_less(T) invariant; freeze on clean cut cnt==n1 (then sel = K<T),
// else T ends at K_(n1-1) (then sel = K<=T). n1==0 exits via cnt==0 cut.
// ---------------------------------------------------------------------------

#define ROTL(x, r) __builtin_amdgcn_alignbit((x), (x), 32u - (r))

// Threefry-2x32, 20 rounds, key (0, 42), block (0, i). Returns w0 ^ w1.
__device__ __forceinline__ u32 threefry_xor(u32 i) {
  const u32 ks0 = 0u;
  const u32 ks1 = 42u;
  const u32 ks2 = 0x1BD11BF0u;   // 0x1BD11BDA ^ 0 ^ 42
  u32 x0 = 0u + ks0;
  u32 x1 = i + ks1;
#define TFR(r) { x0 += x1; x1 = ROTL(x1, r##u); x1 ^= x0; }
  TFR(13) TFR(15) TFR(26) TFR(6)
  x0 += ks1; x1 += ks2 + 1u;
  TFR(17) TFR(29) TFR(16) TFR(24)
  x0 += ks2; x1 += ks0 + 2u;
  TFR(13) TFR(15) TFR(26) TFR(6)
  x0 += ks0; x1 += ks1 + 3u;
  TFR(17) TFR(29) TFR(16) TFR(24)
  x0 += ks1; x1 += ks2 + 4u;
  TFR(13) TFR(15) TFR(26) TFR(6)
  x0 += ks2; x1 += ks0 + 5u;
#undef TFR
  return x0 ^ x1;
}

// One wave64 owns FOUR rows of 256 bits; lane owns bits b = 4*lane + {0..3}
// of each row. Key K = bits[31:9]<<8 | b  (31-bit, distinct within a row).
__global__ __launch_bounds__(256) void bitinput_kernel(
    const float* __restrict__ x, float* __restrict__ out, int nrows) {
  const int lane  = threadIdx.x & 63;
  const int wid   = threadIdx.x >> 6;
  const int row0  = ((blockIdx.x << 2) + wid) << 2;   // 4 rows per wave
  if (row0 >= nrows) return;

  const u32 idx0 = (u32)lane << 2;                    // elem index within row

  // ---- PRNG: 16 chains; pack distinct keys K = (m23<<8)|idx ----
  u32 K[4][4];
#pragma unroll
  for (int r = 0; r < 4; ++r) {
    const u32 gbase = ((u32)(row0 + r)) << 8;         // flat element index base
#pragma unroll
    for (int k = 0; k < 4; ++k) {
      const u32 b = idx0 + (u32)k;
      K[r][k] = ((threefry_xor(gbase + b) >> 1) & 0x7FFFFF00u) | b;
    }
  }

  // n1_r = round-half-even(x*256); exact in f32. Wave-uniform scalars.
  int n1[4];
#pragma unroll
  for (int r = 0; r < 4; ++r)
    n1[r] = __builtin_amdgcn_readfirstlane((int)rintf(x[row0 + r] * 256.0f));

  // ---- 4 interleaved radix searches; all bookkeeping wave-uniform (SALU) ----
  u32 T0 = 0u, T1 = 0u, T2 = 0u, T3 = 0u;
  u32 d0 = 0u, d1 = 0u, d2 = 0u, d3 = 0u;    // done flags (0/1)
#pragma unroll 1
  for (int bit = 30; bit >= 0; --bit) {
    const u32 b = 1u << bit;
    {
      const u32 mid = T0 | b;
      const u32 cnt = (u32)(__popcll(__ballot(K[0][0] < mid))
                          + __popcll(__ballot(K[0][1] < mid))
                          + __popcll(__ballot(K[0][2] < mid))
                          + __popcll(__ballot(K[0][3] < mid)));
      T0 = (!d0 && cnt <= (u32)n1[0]) ? mid : T0;
      d0 |= (u32)(cnt == (u32)n1[0]);
    }
    {
      const u32 mid = T1 | b;
      const u32 cnt = (u32)(__popcll(__ballot(K[1][0] < mid))
                          + __popcll(__ballot(K[1][1] < mid))
                          + __popcll(__ballot(K[1][2] < mid))
                          + __popcll(__ballot(K[1][3] < mid)));
      T1 = (!d1 && cnt <= (u32)n1[1]) ? mid : T1;
      d1 |= (u32)(cnt == (u32)n1[1]);
    }
    {
      const u32 mid = T2 | b;
      const u32 cnt = (u32)(__popcll(__ballot(K[2][0] < mid))
                          + __popcll(__ballot(K[2][1] < mid))
                          + __popcll(__ballot(K[2][2] < mid))
                          + __popcll(__ballot(K[2][3] < mid)));
      T2 = (!d2 && cnt <= (u32)n1[2]) ? mid : T2;
      d2 |= (u32)(cnt == (u32)n1[2]);
    }
    {
      const u32 mid = T3 | b;
      const u32 cnt = (u32)(__popcll(__ballot(K[3][0] < mid))
                          + __popcll(__ballot(K[3][1] < mid))
                          + __popcll(__ballot(K[3][2] < mid))
                          + __popcll(__ballot(K[3][3] < mid)));
      T3 = (!d3 && cnt <= (u32)n1[3]) ? mid : T3;
      d3 |= (u32)(cnt == (u32)n1[3]);
    }
    if (d0 & d1 & d2 & d3) break;   // all uniform -> s_cbranch
  }

  // ---- emit: done -> K < T (clean cut); else K <= T (T = K_(n1-1)) ----
  const u32 S0 = d0 ? T0 : (T0 + 1u);
  const u32 S1 = d1 ? T1 : (T1 + 1u);
  const u32 S2 = d2 ? T2 : (T2 + 1u);
  const u32 S3 = d3 ? T3 : (T3 + 1u);
  const u32 Ts[4] = {S0, S1, S2, S3};
#pragma unroll
  for (int r = 0; r < 4; ++r) {
    float4 o;
    o.x = (K[r][0] < Ts[r]) ? 1.0f : 0.0f;
    o.y = (K[r][1] < Ts[r]) ? 1.0f : 0.0f;
    o.z = (K[r][2] < Ts[r]) ? 1.0f : 0.0f;
    o.w = (K[r][3] < Ts[r]) ? 1.0f : 0.0f;
    reinterpret_cast<float4*>(out)[((row0 + r) << 6) + lane] = o;
  }
}

extern "C" void kernel_launch(void* const* d_in, const int* in_sizes, int n_in,
                              void* d_out, int out_size, void* d_ws, size_t ws_size,
                              hipStream_t stream) {
  const float* x = (const float*)d_in[0];
  float* out = (float*)d_out;
  const int nrows = in_sizes[0];                 // 256*1024 = 262144 bitstreams
  // 4 waves/block, 4 rows/wave -> 16 rows/block
  const int blocks = (nrows + 15) >> 4;
  hipLaunchKernelGGL(bitinput_kernel, dim3(blocks), dim3(256), 0, stream,
                     x, out, nrows);
}